// Round 6
// baseline (384.646 us; speedup 1.0000x reference)
//
#include <hip/hip_runtime.h>

// Problem constants
#define BB 4
#define SS 4096
#define DIN 1024      // K for both GEMMs
#define DH 1024       // combined fast+slow channels
#define PN 2048       // GEMM1 logical output cols (z -> Zarr, h~ -> Harr)
#define MM (BB*SS)    // 16384 rows
#define NCC 16        // scan chunks per sequence
#define CLL 256       // chunk length (NCC*CLL == SS)
#define NCHAIN (BB*4) // 16 lookback chains (batch x channel-group)

typedef unsigned short ushort_t;
typedef __attribute__((ext_vector_type(8))) short bf16x8;
typedef __attribute__((ext_vector_type(4))) float f32x4;
typedef __attribute__((ext_vector_type(4))) unsigned short u16x4;

__device__ inline float bf2f(ushort_t u) {
    union { float f; unsigned int i; } v; v.i = ((unsigned int)u) << 16; return v.f;
}
__device__ inline ushort_t f2bf(float f) {
    union { float f; unsigned int i; } v; v.f = f;
    unsigned int r = v.i + 0x7fffu + ((v.i >> 16) & 1u);  // round-to-nearest-even
    return (ushort_t)(r >> 16);
}
__device__ inline float sigmoidf_(float x) { return 1.0f / (1.0f + __expf(-x)); }

__device__ inline void load_lds16(const void* g, void* l) {
    __builtin_amdgcn_global_load_lds(
        (const __attribute__((address_space(1))) void*)g,
        (__attribute__((address_space(3))) void*)l, 16, 0, 0);
}

// ---------------------------------------------------------------------------
// Fallback (ws too small telemetry): write fp32 zeros to out.
__global__ void zero_out_kernel(float* out, int n) {
    int i = blockIdx.x * 256 + threadIdx.x;
    if (i < n) out[i] = 0.0f;
}

// ---------------------------------------------------------------------------
// Fused prep kernel, region-switched on blockIdx.x:
//  [0,512):        transpose 4x (1024x512 fp32 -> bf16 NxK) into WcatT
//  [512,768):      transpose Wg (1024x1024) into WgT
//  [768,17152):    cvt x fp32 -> bf16 (Xb)
//  [17152,17160):  bias concat (fp32)
//  17160:          zero scan lookback states
#define PREP_NBLK 17161
__global__ __launch_bounds__(256) void prep_kernel(
    const float* __restrict__ x,
    const float* __restrict__ Wzf, const float* __restrict__ Wzs,
    const float* __restrict__ Whf, const float* __restrict__ Whs,
    const float* __restrict__ Wg,
    const float* __restrict__ bzf, const float* __restrict__ bzs,
    const float* __restrict__ bhf, const float* __restrict__ bhs,
    ushort_t* __restrict__ WcatT, ushort_t* __restrict__ WgT,
    ushort_t* __restrict__ Xb, float* __restrict__ bcat, int* __restrict__ states)
{
    __shared__ ushort_t tile[64][65];
    const int bx = blockIdx.x, tid = threadIdx.x;

    if (bx < 768) {
        // transpose region: dst[n][k] = bf16(src[k][n])
        const float* src; ushort_t* dst; int srcN, t;
        if (bx < 512) {
            int wi = bx >> 7; t = bx & 127; srcN = 512;
            const float* S[4] = {Wzf, Wzs, Whf, Whs};
            src = S[wi];
            dst = WcatT + (size_t)(wi * 512) * DIN;
        } else {
            t = bx - 512; srcN = 1024; src = Wg; dst = WgT;
        }
        const int k0 = (t & 15) * 64, n0 = (t >> 4) * 64;
        const int tx = tid & 63, ty = tid >> 6;
        #pragma unroll
        for (int i = ty; i < 64; i += 4)
            tile[i][tx] = f2bf(src[(size_t)(k0 + i) * srcN + n0 + tx]);
        __syncthreads();
        #pragma unroll
        for (int i = ty; i < 64; i += 4)
            dst[(size_t)(n0 + i) * DIN + k0 + tx] = tile[tx][i];
    } else if (bx < 17152) {
        // cvt x region: block handles 1024 elements
        size_t i = ((size_t)(bx - 768) * 256 + tid) * 4;
        float4 v = *(const float4*)(x + i);
        u16x4 o;
        o.x = f2bf(v.x); o.y = f2bf(v.y); o.z = f2bf(v.z); o.w = f2bf(v.w);
        *(u16x4*)(Xb + i) = o;
    } else if (bx < 17160) {
        int i = (bx - 17152) * 256 + tid;  // 0..2047
        float v = (i < 512) ? bzf[i] : (i < 1024) ? bzs[i - 512]
                : (i < 1536) ? bhf[i - 1024] : bhs[i - 1536];
        bcat[i] = v;
    } else {
        if (tid < NCHAIN * NCC) states[tid] = 0;
    }
}

// ---------------------------------------------------------------------------
// GEMM: C(M x N) = A(M x K, bf16 rm, row stride lda) * Bt(N x K, bf16 rm)^T
// 128x128 tile, BK=64, 256 threads (4 waves 2x2, each 64x64 via 4x4 mfma 16x16x32).
// 1-D grid with XCD-aware swizzle: id&7 = xcd slot; per-XCD, NB consecutive
// work items share one A-tile -> each A-tile fetched into exactly one XCD L2.
// LDS XOR-swizzled (chunk p = c ^ (r&7)) -> 0 bank conflicts [round 5].
// EPI=0 (N=2048): col<1024  -> Zarr = bf16(sigmoid(acc+bias)), else Harr = bf16(acc+bias)
// EPI=1 (N=1024): Out = sigmoid(acc + bg[col]) * bf2f(Hbf[row*DH+col])  (fp32)
template <int EPI, int NB>
__global__ __launch_bounds__(256) void gemm_kernel(
    const ushort_t* __restrict__ A, const ushort_t* __restrict__ Bt,
    int K, int lda,
    const float* __restrict__ bias,
    ushort_t* __restrict__ Zarr, ushort_t* __restrict__ Harr,
    const float* __restrict__ bg, const ushort_t* __restrict__ Hbf,
    float* __restrict__ Out)
{
    __shared__ alignas(16) ushort_t As[128 * 64];
    __shared__ alignas(16) ushort_t Bs[128 * 64];

    const int tid  = threadIdx.x;
    const int lane = tid & 63;
    const int wave = tid >> 6;
    const int wm   = wave & 1;
    const int wn   = wave >> 1;
    const int lrow = lane & 15;
    const int kgrp = lane >> 4;

    // XCD-aware work mapping
    const int id  = blockIdx.x;
    const int xcd = id & 7;
    const int s   = id >> 3;
    const int mBase = (xcd + 8 * (s / NB)) * 128;
    const int nBase = (s % NB) * 128;

    f32x4 acc[4][4] = {};

    const ushort_t* Ablk = A  + (size_t)mBase * lda;
    const ushort_t* Bblk = Bt + (size_t)nBase * K;

    for (int k0 = 0; k0 < K; k0 += 64) {
        #pragma unroll
        for (int i = 0; i < 4; i++) {
            int idx = i * 256 + tid;                 // 0..1023 chunks of 16B
            int r   = idx >> 3;                      // row 0..127
            int cc  = ((idx & 7) ^ (r & 7)) * 8;     // swizzled source column
            load_lds16(Ablk + (size_t)r * lda + k0 + cc, &As[idx * 8]);
            load_lds16(Bblk + (size_t)r * K   + k0 + cc, &Bs[idx * 8]);
        }
        __syncthreads();

        #pragma unroll
        for (int kk = 0; kk < 64; kk += 32) {
            const int c0 = (kk >> 3) + kgrp;
            bf16x8 af[4], bfr[4];
            #pragma unroll
            for (int mt = 0; mt < 4; mt++) {
                int r = wm * 64 + mt * 16 + lrow;
                af[mt] = *(const bf16x8*)&As[r * 64 + (c0 ^ (r & 7)) * 8];
            }
            #pragma unroll
            for (int nt = 0; nt < 4; nt++) {
                int r = wn * 64 + nt * 16 + lrow;
                bfr[nt] = *(const bf16x8*)&Bs[r * 64 + (c0 ^ (r & 7)) * 8];
            }
            #pragma unroll
            for (int mt = 0; mt < 4; mt++)
                #pragma unroll
                for (int nt = 0; nt < 4; nt++)
                    acc[mt][nt] = __builtin_amdgcn_mfma_f32_16x16x32_bf16(
                        af[mt], bfr[nt], acc[mt][nt], 0, 0, 0);
        }
        __syncthreads();
    }

    // Epilogue. C/D layout: col = lane&15, row = (lane>>4)*4 + reg  [m89/m91]
    const int row0  = mBase + wm * 64;
    const int col0  = nBase + wn * 64;
    const int rquad = (lane >> 4) * 4;

    if (EPI == 0) {
        const bool isz = (nBase < DH);
        ushort_t* Dst  = isz ? Zarr : Harr;
        const int csub = isz ? 0 : DH;
        #pragma unroll
        for (int nt = 0; nt < 4; nt++) {
            int col  = col0 + nt * 16 + lrow;
            float bv = bias[col];
            int dcol = col - csub;
            #pragma unroll
            for (int mt = 0; mt < 4; mt++) {
                int row = row0 + mt * 16 + rquad;
                ushort_t* p = Dst + (size_t)row * DH + dcol;
                #pragma unroll
                for (int r = 0; r < 4; r++) {
                    float v = acc[mt][nt][r] + bv;
                    if (isz) v = sigmoidf_(v);
                    p[(size_t)r * DH] = f2bf(v);
                }
            }
        }
    } else {
        #pragma unroll
        for (int nt = 0; nt < 4; nt++) {
            int col  = col0 + nt * 16 + lrow;
            float bv = bg[col];
            #pragma unroll
            for (int mt = 0; mt < 4; mt++) {
                int row = row0 + mt * 16 + rquad;
                #pragma unroll
                for (int r = 0; r < 4; r++) {
                    float g = sigmoidf_(acc[mt][nt][r] + bv);
                    float h = bf2f(Hbf[(size_t)(row + r) * DH + col]);
                    Out[(size_t)(row + r) * DH + col] = g * h;
                }
            }
        }
    }
}

// ---------------------------------------------------------------------------
// Single-pass scan with decoupled lookback (Merrill-Garland / rocPRIM style).
// h_t = (1-z)*h + z*h~. Chain = (batch, channel-group of 256); 16 chunks of
// 256 steps each. Block = one (chain, chunk). States: 0=empty, 1=AGG, 2=PREFIX.
// grid (4 cgroup, NCC chunk, BB batch) -> linear id monotone in chunk.
__global__ __launch_bounds__(256) void scan_lookback(
    const ushort_t* __restrict__ Zarr, ushort_t* Harr,
    float* __restrict__ AggA, float* __restrict__ AggB,
    float* __restrict__ PreB, int* __restrict__ states)
{
    const int tid   = threadIdx.x;
    const int cg    = blockIdx.x;
    const int j     = blockIdx.y;            // chunk
    const int b     = blockIdx.z;
    const int chain = b * 4 + cg;
    const int c     = cg * 256 + tid;

    const size_t s0 = ((size_t)b * SS + (size_t)j * CLL) * DH + c;
    const ushort_t* Zp = Zarr + s0;
    ushort_t*       Hp = Harr + s0;

    // Pass 1: local aggregate (A,B): h_end = A*h_start + B
    float A = 1.0f, Bv = 0.0f;
    #pragma unroll 4
    for (int t = 0; t < CLL; t++) {
        float z  = bf2f(Zp[(size_t)t * DH]);
        float ht = bf2f(Hp[(size_t)t * DH]);
        float a  = 1.0f - z;
        A  = A * a;
        Bv = a * Bv + z * ht;
    }

    const size_t ij = (size_t)(chain * NCC + j) * 256 + tid;
    __shared__ int s_st;
    float h_prev;

    if (j == 0) {
        h_prev = 0.0f;
    } else {
        // publish AGG
        AggA[ij] = A; AggB[ij] = Bv;
        __threadfence();
        __syncthreads();
        if (tid == 0)
            __hip_atomic_store(&states[chain * NCC + j], 1, __ATOMIC_RELEASE,
                               __HIP_MEMORY_SCOPE_AGENT);
        // lookback
        float fA = 1.0f, fB = 0.0f;
        int k = j - 1;
        for (;;) {
            if (tid == 0) {
                int st;
                do {
                    st = __hip_atomic_load(&states[chain * NCC + k], __ATOMIC_ACQUIRE,
                                           __HIP_MEMORY_SCOPE_AGENT);
                    if (st == 0) __builtin_amdgcn_s_sleep(2);
                } while (st == 0);
                s_st = st;
            }
            __syncthreads();
            const int st = s_st;
            __syncthreads();
            const size_t ik = (size_t)(chain * NCC + k) * 256 + tid;
            if (st == 2) { h_prev = fA * PreB[ik] + fB; break; }
            float gA = AggA[ik], gB = AggB[ik];
            fB = fA * gB + fB;
            fA = fA * gA;
            if (--k < 0) { h_prev = fB; break; }  // safety (chunk 0 publishes PREFIX)
        }
    }

    // publish PREFIX (h at end of this chunk)
    PreB[ij] = A * h_prev + Bv;
    __threadfence();
    __syncthreads();
    if (tid == 0)
        __hip_atomic_store(&states[chain * NCC + j], 2, __ATOMIC_RELEASE,
                           __HIP_MEMORY_SCOPE_AGENT);

    // Pass 2: apply (re-reads are L2-hot: 256 KB/block), write h over Harr
    float h = h_prev;
    #pragma unroll 4
    for (int t = 0; t < CLL; t++) {
        float z  = bf2f(Zp[(size_t)t * DH]);
        float ht = bf2f(Hp[(size_t)t * DH]);
        h = (1.0f - z) * h + z * ht;
        Hp[(size_t)t * DH] = f2bf(h);
    }
}

// ---------------------------------------------------------------------------
extern "C" void kernel_launch(void* const* d_in, const int* in_sizes, int n_in,
                              void* d_out, int out_size, void* d_ws, size_t ws_size,
                              hipStream_t stream)
{
    const float* x   = (const float*)d_in[0];
    const float* Wzf = (const float*)d_in[1];
    const float* bzf = (const float*)d_in[2];
    const float* Whf = (const float*)d_in[3];
    const float* bhf = (const float*)d_in[4];
    const float* Wzs = (const float*)d_in[5];
    const float* bzs = (const float*)d_in[6];
    const float* Whs = (const float*)d_in[7];
    const float* bhs = (const float*)d_in[8];
    const float* Wg  = (const float*)d_in[9];
    const float* bg  = (const float*)d_in[10];

    const size_t NEED = (size_t)42 << 20;
    if (ws_size < NEED) {
        zero_out_kernel<<<(MM * DH + 255) / 256, 256, 0, stream>>>((float*)d_out, MM * DH);
        return;
    }

    // Workspace layout:
    char* ws = (char*)d_ws;
    ushort_t* WcatT  = (ushort_t*)(ws);                                    // 0..4 MiB
    ushort_t* WgT    = (ushort_t*)(ws + ((size_t)4 << 20));                // 4..6 MiB
    float*    bcat   = (float*)   (ws + ((size_t)6 << 20));                // 8 KiB
    float*    AggA   = (float*)   (ws + ((size_t)6 << 20) + (64 << 10));   // 256 KiB
    float*    AggB   = (float*)   (ws + ((size_t)6 << 20) + (320 << 10));  // 256 KiB
    float*    PreB   = (float*)   (ws + ((size_t)6 << 20) + (576 << 10));  // 256 KiB
    int*      states = (int*)     (ws + ((size_t)6 << 20) + (832 << 10));  // 1 KiB
    ushort_t* Harr   = (ushort_t*)(ws + ((size_t)10 << 20));               // 10..42 MiB

    // d_out (64 MiB fp32) doubles as bf16 scratch until GEMM2 overwrites it:
    ushort_t* Xb   = (ushort_t*)d_out;              // [0..32 MiB): x in bf16
    ushort_t* Zarr = Xb + (size_t)MM * DH;          // [32..64 MiB): post-sigmoid z

    dim3 blk(256);

    // Fused prep: 5 transposes + x cvt + bias concat + state zeroing
    prep_kernel<<<PREP_NBLK, blk, 0, stream>>>(
        x, Wzf, Wzs, Whf, Whs, Wg, bzf, bzs, bhf, bhs,
        WcatT, WgT, Xb, bcat, states);

    // GEMM1: Zarr = sigmoid(Xb@Wz+bz), Harr = Xb@Wh+bh   (M=16384, N=2048, K=1024)
    gemm_kernel<0, PN / 128><<<(MM / 128) * (PN / 128), blk, 0, stream>>>(
        Xb, WcatT, DIN, /*lda=*/DIN, bcat, Zarr, Harr, nullptr, nullptr, nullptr);

    // Single-pass chunked scan with decoupled lookback (h in place over Harr)
    scan_lookback<<<dim3(4, NCC, BB), blk, 0, stream>>>(
        Zarr, Harr, AggA, AggB, PreB, states);

    // GEMM2: out = sigmoid(H @ Wg + bg) * H   (fp32 out, overwrites all of d_out)
    gemm_kernel<1, DH / 128><<<(MM / 128) * (DH / 128), blk, 0, stream>>>(
        Harr, WgT, DIN, /*lda=*/DH, nullptr, nullptr, nullptr, bg, /*Hbf=*/Harr,
        (float*)d_out);
}

// Round 7
// 331.017 us; speedup vs baseline: 1.1620x; 1.1620x over previous
//
#include <hip/hip_runtime.h>

// Problem constants
#define BB 4
#define SS 4096
#define DIN 1024      // K for both GEMMs
#define DH 1024       // combined fast+slow channels
#define PN 2048       // GEMM1 logical output cols (z -> Zarr, h~ -> Harr)
#define MM (BB*SS)    // 16384 rows
#define NC 64         // scan chunks
#define CL 64         // chunk length (NC*CL == SS)

typedef unsigned short ushort_t;
typedef __attribute__((ext_vector_type(8))) short bf16x8;
typedef __attribute__((ext_vector_type(4))) float f32x4;
typedef __attribute__((ext_vector_type(4))) unsigned short u16x4;

__device__ inline float bf2f(ushort_t u) {
    union { float f; unsigned int i; } v; v.i = ((unsigned int)u) << 16; return v.f;
}
__device__ inline ushort_t f2bf(float f) {
    union { float f; unsigned int i; } v; v.f = f;
    unsigned int r = v.i + 0x7fffu + ((v.i >> 16) & 1u);  // round-to-nearest-even
    return (ushort_t)(r >> 16);
}
__device__ inline float sigmoidf_(float x) { return 1.0f / (1.0f + __expf(-x)); }

__device__ inline void load_lds16(const void* g, void* l) {
    __builtin_amdgcn_global_load_lds(
        (const __attribute__((address_space(1))) void*)g,
        (__attribute__((address_space(3))) void*)l, 16, 0, 0);
}

// ---------------------------------------------------------------------------
// Fallback (ws too small telemetry): write fp32 zeros to out.
__global__ void zero_out_kernel(float* out, int n) {
    int i = blockIdx.x * 256 + threadIdx.x;
    if (i < n) out[i] = 0.0f;
}

// ---------------------------------------------------------------------------
// Fused prep kernel, region-switched on blockIdx.x:
//  [0,512):        transpose 4x (1024x512 fp32 -> bf16 NxK) into WcatT
//  [512,768):      transpose Wg (1024x1024) into WgT
//  [768,17152):    cvt x fp32 -> bf16 (Xb)
//  [17152,17160):  bias concat (fp32)
#define PREP_NBLK 17160
__global__ __launch_bounds__(256) void prep_kernel(
    const float* __restrict__ x,
    const float* __restrict__ Wzf, const float* __restrict__ Wzs,
    const float* __restrict__ Whf, const float* __restrict__ Whs,
    const float* __restrict__ Wg,
    const float* __restrict__ bzf, const float* __restrict__ bzs,
    const float* __restrict__ bhf, const float* __restrict__ bhs,
    ushort_t* __restrict__ WcatT, ushort_t* __restrict__ WgT,
    ushort_t* __restrict__ Xb, float* __restrict__ bcat)
{
    __shared__ ushort_t tile[64][65];
    const int bx = blockIdx.x, tid = threadIdx.x;

    if (bx < 768) {
        // transpose region: dst[n][k] = bf16(src[k][n])
        const float* src; ushort_t* dst; int srcN, t;
        if (bx < 512) {
            int wi = bx >> 7; t = bx & 127; srcN = 512;
            const float* S[4] = {Wzf, Wzs, Whf, Whs};
            src = S[wi];
            dst = WcatT + (size_t)(wi * 512) * DIN;
        } else {
            t = bx - 512; srcN = 1024; src = Wg; dst = WgT;
        }
        const int k0 = (t & 15) * 64, n0 = (t >> 4) * 64;
        const int tx = tid & 63, ty = tid >> 6;
        #pragma unroll
        for (int i = ty; i < 64; i += 4)
            tile[i][tx] = f2bf(src[(size_t)(k0 + i) * srcN + n0 + tx]);
        __syncthreads();
        #pragma unroll
        for (int i = ty; i < 64; i += 4)
            dst[(size_t)(n0 + i) * DIN + k0 + tx] = tile[tx][i];
    } else if (bx < 17152) {
        // cvt x region: block handles 1024 elements
        size_t i = ((size_t)(bx - 768) * 256 + tid) * 4;
        float4 v = *(const float4*)(x + i);
        u16x4 o;
        o.x = f2bf(v.x); o.y = f2bf(v.y); o.z = f2bf(v.z); o.w = f2bf(v.w);
        *(u16x4*)(Xb + i) = o;
    } else {
        int i = (bx - 17152) * 256 + tid;  // 0..2047
        float v = (i < 512) ? bzf[i] : (i < 1024) ? bzs[i - 512]
                : (i < 1536) ? bhf[i - 1024] : bhs[i - 1536];
        bcat[i] = v;
    }
}

// ---------------------------------------------------------------------------
// GEMM: C(M x N) = A(M x K, bf16 rm, row stride lda) * Bt(N x K, bf16 rm)^T
// 128x128 tile, BK=64, 256 threads (4 waves 2x2, each 64x64 via 4x4 mfma 16x16x32).
// 1-D grid with XCD-aware swizzle. LDS XOR-swizzled -> 0 bank conflicts [r5].
// EPI=0 (N=2048): col<1024  -> Zarr = bf16(sigmoid(acc+bias)), else Harr = bf16(acc+bias)
// EPI=1 (N=1024): Out = sigmoid(acc + bg[col]) * bf2f(Hbf[row*DH+col])  (fp32)
template <int EPI, int NB>
__global__ __launch_bounds__(256) void gemm_kernel(
    const ushort_t* __restrict__ A, const ushort_t* __restrict__ Bt,
    int K, int lda,
    const float* __restrict__ bias,
    ushort_t* __restrict__ Zarr, ushort_t* __restrict__ Harr,
    const float* __restrict__ bg, const ushort_t* __restrict__ Hbf,
    float* __restrict__ Out)
{
    __shared__ alignas(16) ushort_t As[128 * 64];
    __shared__ alignas(16) ushort_t Bs[128 * 64];

    const int tid  = threadIdx.x;
    const int lane = tid & 63;
    const int wave = tid >> 6;
    const int wm   = wave & 1;
    const int wn   = wave >> 1;
    const int lrow = lane & 15;
    const int kgrp = lane >> 4;

    // XCD-aware work mapping
    const int id  = blockIdx.x;
    const int xcd = id & 7;
    const int s   = id >> 3;
    const int mBase = (xcd + 8 * (s / NB)) * 128;
    const int nBase = (s % NB) * 128;

    f32x4 acc[4][4] = {};

    const ushort_t* Ablk = A  + (size_t)mBase * lda;
    const ushort_t* Bblk = Bt + (size_t)nBase * K;

    for (int k0 = 0; k0 < K; k0 += 64) {
        #pragma unroll
        for (int i = 0; i < 4; i++) {
            int idx = i * 256 + tid;                 // 0..1023 chunks of 16B
            int r   = idx >> 3;                      // row 0..127
            int cc  = ((idx & 7) ^ (r & 7)) * 8;     // swizzled source column
            load_lds16(Ablk + (size_t)r * lda + k0 + cc, &As[idx * 8]);
            load_lds16(Bblk + (size_t)r * K   + k0 + cc, &Bs[idx * 8]);
        }
        __syncthreads();

        #pragma unroll
        for (int kk = 0; kk < 64; kk += 32) {
            const int c0 = (kk >> 3) + kgrp;
            bf16x8 af[4], bfr[4];
            #pragma unroll
            for (int mt = 0; mt < 4; mt++) {
                int r = wm * 64 + mt * 16 + lrow;
                af[mt] = *(const bf16x8*)&As[r * 64 + (c0 ^ (r & 7)) * 8];
            }
            #pragma unroll
            for (int nt = 0; nt < 4; nt++) {
                int r = wn * 64 + nt * 16 + lrow;
                bfr[nt] = *(const bf16x8*)&Bs[r * 64 + (c0 ^ (r & 7)) * 8];
            }
            #pragma unroll
            for (int mt = 0; mt < 4; mt++)
                #pragma unroll
                for (int nt = 0; nt < 4; nt++)
                    acc[mt][nt] = __builtin_amdgcn_mfma_f32_16x16x32_bf16(
                        af[mt], bfr[nt], acc[mt][nt], 0, 0, 0);
        }
        __syncthreads();
    }

    // Epilogue. C/D layout: col = lane&15, row = (lane>>4)*4 + reg  [m89/m91]
    const int row0  = mBase + wm * 64;
    const int col0  = nBase + wn * 64;
    const int rquad = (lane >> 4) * 4;

    if (EPI == 0) {
        const bool isz = (nBase < DH);
        ushort_t* Dst  = isz ? Zarr : Harr;
        const int csub = isz ? 0 : DH;
        #pragma unroll
        for (int nt = 0; nt < 4; nt++) {
            int col  = col0 + nt * 16 + lrow;
            float bv = bias[col];
            int dcol = col - csub;
            #pragma unroll
            for (int mt = 0; mt < 4; mt++) {
                int row = row0 + mt * 16 + rquad;
                ushort_t* p = Dst + (size_t)row * DH + dcol;
                #pragma unroll
                for (int r = 0; r < 4; r++) {
                    float v = acc[mt][nt][r] + bv;
                    if (isz) v = sigmoidf_(v);
                    p[(size_t)r * DH] = f2bf(v);
                }
            }
        }
    } else {
        #pragma unroll
        for (int nt = 0; nt < 4; nt++) {
            int col  = col0 + nt * 16 + lrow;
            float bv = bg[col];
            #pragma unroll
            for (int mt = 0; mt < 4; mt++) {
                int row = row0 + mt * 16 + rquad;
                #pragma unroll
                for (int r = 0; r < 4; r++) {
                    float g = sigmoidf_(acc[mt][nt][r] + bv);
                    float h = bf2f(Hbf[(size_t)(row + r) * DH + col]);
                    Out[(size_t)(row + r) * DH + col] = g * h;
                }
            }
        }
    }
}

// ---------------------------------------------------------------------------
// Scan pass 1: per-chunk aggregates, 4 channels/thread (u16x4 = 8B loads),
// 4 independent recurrence chains per thread for ILP. Block covers all 1024
// channels. grid (NC, BB), block 256.
__global__ __launch_bounds__(256) void scan_chunk_agg(
    const ushort_t* __restrict__ Zarr, const ushort_t* __restrict__ Harr,
    float* __restrict__ Agg, float* __restrict__ Bagg)
{
    const int c4    = threadIdx.x * 4;   // channel base 0..1020
    const int chunk = blockIdx.x;
    const int b     = blockIdx.y;
    const size_t s0 = ((size_t)b * SS + (size_t)chunk * CL) * DH + c4;
    const ushort_t* Zp = Zarr + s0;
    const ushort_t* Hp = Harr + s0;

    float A0 = 1.0f, A1 = 1.0f, A2 = 1.0f, A3 = 1.0f;
    float B0 = 0.0f, B1 = 0.0f, B2 = 0.0f, B3 = 0.0f;
    #pragma unroll 8
    for (int t = 0; t < CL; t++) {
        u16x4 zv = *(const u16x4*)(Zp + (size_t)t * DH);
        u16x4 hv = *(const u16x4*)(Hp + (size_t)t * DH);
        float z0 = bf2f(zv.x), z1 = bf2f(zv.y), z2 = bf2f(zv.z), z3 = bf2f(zv.w);
        float h0 = bf2f(hv.x), h1 = bf2f(hv.y), h2 = bf2f(hv.z), h3 = bf2f(hv.w);
        A0 *= 1.0f - z0;  B0 = (1.0f - z0) * B0 + z0 * h0;
        A1 *= 1.0f - z1;  B1 = (1.0f - z1) * B1 + z1 * h1;
        A2 *= 1.0f - z2;  B2 = (1.0f - z2) * B2 + z2 * h2;
        A3 *= 1.0f - z3;  B3 = (1.0f - z3) * B3 + z3 * h3;
    }
    const size_t idx = ((size_t)(b * NC + chunk)) * DH + c4;
    *(float4*)(Agg  + idx) = make_float4(A0, A1, A2, A3);
    *(float4*)(Bagg + idx) = make_float4(B0, B1, B2, B3);
}

// Scan pass 2: carry across chunks. 4096 threads, 64 sequential L2-hot steps.
__global__ void scan_carry(const float* __restrict__ Agg, const float* __restrict__ Bagg,
                           float* __restrict__ Hinit)
{
    const int i = blockIdx.x * 256 + threadIdx.x;  // 0..4095
    const int b = i >> 10, c = i & 1023;
    float h = 0.0f;
    for (int j = 0; j < NC; j++) {
        const size_t idx = ((size_t)(b * NC + j)) * DH + c;
        Hinit[idx] = h;
        h = Agg[idx] * h + Bagg[idx];
    }
}

// Scan pass 3: re-apply with chunk-initial h (4 ch/thread, vector I/O);
// write h (bf16) in place over Harr.
__global__ __launch_bounds__(256) void scan_apply(
    const ushort_t* __restrict__ Zarr, ushort_t* Harr, const float* __restrict__ Hinit)
{
    const int c4    = threadIdx.x * 4;
    const int chunk = blockIdx.x;
    const int b     = blockIdx.y;
    const size_t s0 = ((size_t)b * SS + (size_t)chunk * CL) * DH + c4;
    const ushort_t* Zp = Zarr + s0;
    ushort_t*       Hp = Harr + s0;

    float4 hi = *(const float4*)(Hinit + ((size_t)(b * NC + chunk)) * DH + c4);
    float h0 = hi.x, h1 = hi.y, h2 = hi.z, h3 = hi.w;
    #pragma unroll 8
    for (int t = 0; t < CL; t++) {
        u16x4 zv = *(const u16x4*)(Zp + (size_t)t * DH);
        u16x4 hv = *(const u16x4*)(Hp + (size_t)t * DH);
        float z0 = bf2f(zv.x), z1 = bf2f(zv.y), z2 = bf2f(zv.z), z3 = bf2f(zv.w);
        float t0 = bf2f(hv.x), t1 = bf2f(hv.y), t2 = bf2f(hv.z), t3 = bf2f(hv.w);
        h0 = (1.0f - z0) * h0 + z0 * t0;
        h1 = (1.0f - z1) * h1 + z1 * t1;
        h2 = (1.0f - z2) * h2 + z2 * t2;
        h3 = (1.0f - z3) * h3 + z3 * t3;
        u16x4 o;
        o.x = f2bf(h0); o.y = f2bf(h1); o.z = f2bf(h2); o.w = f2bf(h3);
        *(u16x4*)(Hp + (size_t)t * DH) = o;
    }
}

// ---------------------------------------------------------------------------
extern "C" void kernel_launch(void* const* d_in, const int* in_sizes, int n_in,
                              void* d_out, int out_size, void* d_ws, size_t ws_size,
                              hipStream_t stream)
{
    const float* x   = (const float*)d_in[0];
    const float* Wzf = (const float*)d_in[1];
    const float* bzf = (const float*)d_in[2];
    const float* Whf = (const float*)d_in[3];
    const float* bhf = (const float*)d_in[4];
    const float* Wzs = (const float*)d_in[5];
    const float* bzs = (const float*)d_in[6];
    const float* Whs = (const float*)d_in[7];
    const float* bhs = (const float*)d_in[8];
    const float* Wg  = (const float*)d_in[9];
    const float* bg  = (const float*)d_in[10];

    const size_t NEED = (size_t)42 << 20;
    if (ws_size < NEED) {
        zero_out_kernel<<<(MM * DH + 255) / 256, 256, 0, stream>>>((float*)d_out, MM * DH);
        return;
    }

    // Workspace layout (42 MiB):
    char* ws = (char*)d_ws;
    ushort_t* WcatT = (ushort_t*)(ws);                                    // 0..4 MiB
    ushort_t* WgT   = (ushort_t*)(ws + ((size_t)4 << 20));                // 4..6 MiB
    float*    bcat  = (float*)   (ws + ((size_t)6 << 20));                // 8 KiB
    float*    Agg   = (float*)   (ws + ((size_t)6 << 20) + (64 << 10));   // 1 MiB
    float*    Bagg  = (float*)   (ws + ((size_t)7 << 20) + (64 << 10));   // 1 MiB
    float*    Hinit = (float*)   (ws + ((size_t)8 << 20) + (64 << 10));   // 1 MiB
    ushort_t* Harr  = (ushort_t*)(ws + ((size_t)10 << 20));               // 10..42 MiB

    // d_out (64 MiB fp32) doubles as bf16 scratch until GEMM2 overwrites it:
    ushort_t* Xb   = (ushort_t*)d_out;              // [0..32 MiB): x in bf16
    ushort_t* Zarr = Xb + (size_t)MM * DH;          // [32..64 MiB): post-sigmoid z

    dim3 blk(256);

    // Fused prep: 5 transposes + x cvt + bias concat
    prep_kernel<<<PREP_NBLK, blk, 0, stream>>>(
        x, Wzf, Wzs, Whf, Whs, Wg, bzf, bzs, bhf, bhs, WcatT, WgT, Xb, bcat);

    // GEMM1: Zarr = sigmoid(Xb@Wz+bz), Harr = Xb@Wh+bh   (M=16384, N=2048, K=1024)
    gemm_kernel<0, PN / 128><<<(MM / 128) * (PN / 128), blk, 0, stream>>>(
        Xb, WcatT, DIN, /*lda=*/DIN, bcat, Zarr, Harr, nullptr, nullptr, nullptr);

    // Chunked scan, 3 deterministic passes (h in place over Harr)
    scan_chunk_agg<<<dim3(NC, BB), blk, 0, stream>>>(Zarr, Harr, Agg, Bagg);
    scan_carry<<<16, 256, 0, stream>>>(Agg, Bagg, Hinit);
    scan_apply<<<dim3(NC, BB), blk, 0, stream>>>(Zarr, Harr, Hinit);

    // GEMM2: out = sigmoid(H @ Wg + bg) * H   (fp32 out, overwrites all of d_out)
    gemm_kernel<1, DH / 128><<<(MM / 128) * (DH / 128), blk, 0, stream>>>(
        Harr, WgT, DIN, /*lda=*/DH, nullptr, nullptr, nullptr, bg, /*Hbf=*/Harr,
        (float*)d_out);
}